// Round 14
// baseline (195.688 us; speedup 1.0000x reference)
//
#include <hip/hip_runtime.h>
#include <hip/hip_fp16.h>

#define N_NODES 100000
#define N_EDGES 1600000
#define IN_C 64
#define HID_C 64
#define OUT_C 16

#define BKT 128        // nodes per dst bucket
#define BSH 7          // dst >> 7 = bucket
#define NBKT 782       // ceil(100000/128)
#define CAP 2560       // slots per bucket (mean 2046, +11 sigma margin)
#define GB 512         // bin sub-blocks in merged pass 1
#define EPB 3125       // edges per bin block (512*3125 = 1.6M exact)
#define NIT 13         // ceil(EPB/256) register-cached edges per thread
#define G1B 1563       // gemm1 sub-blocks = ceil(100000/64)

typedef _Float16 f16x8 __attribute__((ext_vector_type(8)));
typedef float f32x4 __attribute__((ext_vector_type(4)));
typedef float f32x16 __attribute__((ext_vector_type(16)));

// ---------------------------------------------------------------------------
// Merged pass 1: blocks [0,GB) bin edges; blocks [GB, GB+G1B) do GEMM1 (MFMA).
// Bin: dst/src register-cached (one global read), LDS bucket histogram ->
// one global atomicAdd per (block,bucket) reserves bucket range -> scatter.
// ---------------------------------------------------------------------------
__global__ __launch_bounds__(256) void k_merged1(
    const int* __restrict__ src, const int* __restrict__ dst,
    int* __restrict__ gcnt, int* __restrict__ binned,
    const float* __restrict__ x, const float* __restrict__ Wl,
    const float* __restrict__ Wr, const float* __restrict__ b,
    __half* __restrict__ p, __half* __restrict__ q) {
  __shared__ _Float16 sA[64 * 68];    // gemm: [row][k]   | bin: h[] alias
  __shared__ _Float16 sW[128 * 68];   // gemm: [col][k]^T | bin: cur[] alias
  int t = threadIdx.x;

  if (blockIdx.x < GB) {
    int* h   = (int*)sA;              // NBKT ints (3.1 KB)
    int* cur = (int*)sW;              // NBKT ints
    for (int i = t; i < NBKT; i += 256) h[i] = 0;
    __syncthreads();
    int base = blockIdx.x * EPB;
    int end = base + EPB;
    int dv[NIT], sv[NIT];
#pragma unroll
    for (int it = 0; it < NIT; ++it) {
      int e = base + t + it * 256;
      bool ok = (e < end);
      dv[it] = ok ? dst[e] : -1;
      sv[it] = ok ? src[e] : 0;
    }
#pragma unroll
    for (int it = 0; it < NIT; ++it)
      if (dv[it] >= 0) atomicAdd(&h[dv[it] >> BSH], 1);
    __syncthreads();
    for (int i = t; i < NBKT; i += 256) {
      int c = h[i];
      int b0 = (c > 0) ? atomicAdd(&gcnt[i], c) : 0;  // reserve range
      cur[i] = i * CAP + b0;
    }
    __syncthreads();
#pragma unroll
    for (int it = 0; it < NIT; ++it) {
      if (dv[it] >= 0) {
        int d = dv[it];
        int pos = atomicAdd(&cur[d >> BSH], 1);
        binned[pos] = (sv[it] << BSH) | (d & (BKT - 1));
      }
    }
    return;
  }

  // ---------------- gemm1 body ----------------
  int n0 = (blockIdx.x - GB) * 64;

  for (int f = t; f < 1024; f += 256) {
    int r = f >> 4, c4 = f & 15;
    int n = n0 + r;
    float4 v = {0.0f, 0.0f, 0.0f, 0.0f};
    if (n < N_NODES) v = *(const float4*)&x[(size_t)n * 64 + c4 * 4];
    union { _Float16 h[4]; float2 f2; } u;
    u.h[0] = (_Float16)v.x; u.h[1] = (_Float16)v.y;
    u.h[2] = (_Float16)v.z; u.h[3] = (_Float16)v.w;
    *(float2*)&sA[r * 68 + c4 * 4] = u.f2;
  }
  for (int f = t; f < 2048; f += 256) {
    int k = f >> 5, c4 = f & 31;
    float4 w = (c4 < 16) ? *(const float4*)&Wl[k * 64 + c4 * 4]
                         : *(const float4*)&Wr[k * 64 + (c4 - 16) * 4];
    int c = c4 * 4;
    sW[(c + 0) * 68 + k] = (_Float16)w.x;
    sW[(c + 1) * 68 + k] = (_Float16)w.y;
    sW[(c + 2) * 68 + k] = (_Float16)w.z;
    sW[(c + 3) * 68 + k] = (_Float16)w.w;
  }
  __syncthreads();

  int w = t >> 6, lane = t & 63;
  int m = lane & 31, half = lane >> 5;
  int rt = w & 1, cg = w >> 1;

  f32x16 acc[2];
#pragma unroll
  for (int r = 0; r < 16; ++r) { acc[0][r] = 0.0f; acc[1][r] = 0.0f; }

  const _Float16* pA = &sA[(rt * 32 + m) * 68 + half * 8];
  const _Float16* pB0 = &sW[(cg * 64 + m) * 68 + half * 8];
  const _Float16* pB1 = &sW[(cg * 64 + 32 + m) * 68 + half * 8];
#pragma unroll
  for (int kc = 0; kc < 4; ++kc) {
    union { f16x8 v; float2 f2[2]; } a, b0, b1;
    a.f2[0] = *(const float2*)(pA + kc * 16);
    a.f2[1] = *(const float2*)(pA + kc * 16 + 4);
    b0.f2[0] = *(const float2*)(pB0 + kc * 16);
    b0.f2[1] = *(const float2*)(pB0 + kc * 16 + 4);
    b1.f2[0] = *(const float2*)(pB1 + kc * 16);
    b1.f2[1] = *(const float2*)(pB1 + kc * 16 + 4);
    acc[0] = __builtin_amdgcn_mfma_f32_32x32x16_f16(a.v, b0.v, acc[0], 0, 0, 0);
    acc[1] = __builtin_amdgcn_mfma_f32_32x32x16_f16(a.v, b1.v, acc[1], 0, 0, 0);
  }

  if (cg == 0) {
#pragma unroll
    for (int tt = 0; tt < 2; ++tt) {
      int col = tt * 32 + m;
#pragma unroll
      for (int r = 0; r < 16; ++r) {
        int row = (r & 3) + 4 * half + 8 * (r >> 2);
        int n = n0 + rt * 32 + row;
        if (n < N_NODES) p[(size_t)n * 64 + col] = __float2half(acc[tt][r]);
      }
    }
  } else {
    float bias[2] = {b[m], b[32 + m]};
#pragma unroll
    for (int tt = 0; tt < 2; ++tt) {
      int col = tt * 32 + m;
#pragma unroll
      for (int r = 0; r < 16; ++r) {
        int row = (r & 3) + 4 * half + 8 * (r >> 2);
        int n = n0 + rt * 32 + row;
        if (n < N_NODES)
          q[(size_t)n * 64 + col] = __float2half(acc[tt][r] + bias[tt]);
      }
    }
  }
}

// ---------------------------------------------------------------------------
// Fuse1c (finalize ∪ fuse1 ∪ gemm2): one block per 128-node bucket, 1024 thr.
// Phase A: node histogram -> LDS scan -> scatter src into LDS lcsr;
//          export csr/rowstart/cnt for fuse2.
// Phase B: h = relu(mean_j p1[lcsr_j] + q1) -> fp16 LDS sH (128 groups,
//          one node each, 8 lanes x float4).
// Phase C: MFMA 128x32 K=64: 16 waves; waves 0-7 -> p2 tiles, 8-15 -> q2+bias.
//          mfma_f32_16x16x32_f16, one 16-row tile per wave.
// ---------------------------------------------------------------------------
__global__ __launch_bounds__(1024) void k_fuse1c(
    const float4* __restrict__ p1, const int* __restrict__ gcnt,
    const int* __restrict__ binned, const float* __restrict__ W2l,
    const float* __restrict__ W2r, const float* __restrict__ b2,
    const float4* __restrict__ q1, int* __restrict__ csr,
    int* __restrict__ rowstart, int* __restrict__ cnt,
    __half* __restrict__ p2, float* __restrict__ q2) {
  __shared__ int hcnt[BKT];
  __shared__ int hscan[BKT];
  __shared__ int cur[BKT];
  __shared__ int lcsr[CAP];          // 10 KB
  __shared__ _Float16 sH[128 * 68];  // 17.4 KB
  __shared__ _Float16 sW[32 * 68];   // 4.4 KB [col][k]^T: 0-15 W2l, 16-31 W2r
  int b = blockIdx.x;
  int t = threadIdx.x;

  if (t < 512) {  // stage W2^T (512 half4 chunks)
    int k = t >> 3, c4v = t & 7;
    float4 w = (c4v < 4) ? *(const float4*)&W2l[k * 16 + c4v * 4]
                         : *(const float4*)&W2r[k * 16 + (c4v - 4) * 4];
    int c = c4v * 4;
    sW[(c + 0) * 68 + k] = (_Float16)w.x;
    sW[(c + 1) * 68 + k] = (_Float16)w.y;
    sW[(c + 2) * 68 + k] = (_Float16)w.z;
    sW[(c + 3) * 68 + k] = (_Float16)w.w;
  }
  if (t < BKT) hcnt[t] = 0;
  __syncthreads();

  // ---- Phase A ----
  int start = b * CAP;
  int total = gcnt[b];
  for (int i = t; i < total; i += 1024)
    atomicAdd(&hcnt[binned[start + i] & (BKT - 1)], 1);
  __syncthreads();
  int v = 0;
  if (t < BKT) {
    v = hcnt[t];
    hscan[t] = v;
  }
  __syncthreads();
  for (int st = 1; st < BKT; st <<= 1) {
    int a = 0;
    if (t < BKT && t >= st) a = hscan[t - st];
    __syncthreads();
    if (t < BKT) hscan[t] += a;
    __syncthreads();
  }
  if (t < BKT) {
    cur[t] = hscan[t] - v;          // local exclusive start
    int n = (b << BSH) + t;
    if (n < N_NODES) {
      rowstart[n] = start + hscan[t] - v;
      cnt[n] = v;
    }
  }
  __syncthreads();
  for (int i = t; i < total; i += 1024) {
    int vv = binned[start + i];
    int pos = atomicAdd(&cur[vv & (BKT - 1)], 1);
    lcsr[pos] = vv >> BSH;
  }
  __syncthreads();
  for (int i = t; i < total; i += 1024) csr[start + i] = lcsr[i];  // for fuse2

  // ---- Phase B: aggregate + relu -> sH (fp16); 128 groups, 1 node each ----
  {
    int r = t >> 3, c4 = t & 7;
    int n = (b << BSH) + r;
    if (n < N_NODES) {
      int deg = hcnt[r];
      int row = hscan[r] - deg;  // local start in lcsr
      float acc[8];
#pragma unroll
      for (int m = 0; m < 8; ++m) acc[m] = 0.0f;
      int j = 0;
      for (; j + 8 <= deg; j += 8) {
        int idx[8];
#pragma unroll
        for (int u = 0; u < 8; ++u) idx[u] = lcsr[row + j + u];
        float4 av[8];
#pragma unroll
        for (int u = 0; u < 8; ++u) av[u] = p1[idx[u] * 8 + c4];
#pragma unroll
        for (int u = 0; u < 8; ++u) {
          const __half2* h = (const __half2*)&av[u];
#pragma unroll
          for (int m = 0; m < 4; ++m) {
            float2 f = __half22float2(h[m]);
            acc[2 * m] += f.x;
            acc[2 * m + 1] += f.y;
          }
        }
      }
      for (; j < deg; ++j) {
        float4 a = p1[lcsr[row + j] * 8 + c4];
        const __half2* h = (const __half2*)&a;
#pragma unroll
        for (int m = 0; m < 4; ++m) {
          float2 f = __half22float2(h[m]);
          acc[2 * m] += f.x;
          acc[2 * m + 1] += f.y;
        }
      }
      float inv = 1.0f / fmaxf((float)deg, 1.0f);
      float4 qv = q1[n * 8 + c4];
      __half2* qh = (__half2*)&qv;
      union { __half2 h2[2]; float2 f2; } u01, u23;
#pragma unroll
      for (int m = 0; m < 2; ++m) {
        float2 f = __half22float2(qh[m]);
        float2 s;
        s.x = fmaxf(acc[2 * m] * inv + f.x, 0.0f);
        s.y = fmaxf(acc[2 * m + 1] * inv + f.y, 0.0f);
        u01.h2[m] = __float22half2_rn(s);
      }
#pragma unroll
      for (int m = 2; m < 4; ++m) {
        float2 f = __half22float2(qh[m]);
        float2 s;
        s.x = fmaxf(acc[2 * m] * inv + f.x, 0.0f);
        s.y = fmaxf(acc[2 * m + 1] * inv + f.y, 0.0f);
        u23.h2[m - 2] = __float22half2_rn(s);
      }
      *(float2*)&sH[r * 68 + c4 * 8] = u01.f2;
      *(float2*)&sH[r * 68 + c4 * 8 + 4] = u23.f2;
    } else if (r < BKT) {
      // zero pad rows beyond N_NODES so phase C MFMA reads defined data
      *(float2*)&sH[r * 68 + c4 * 8] = make_float2(0.0f, 0.0f);
      *(float2*)&sH[r * 68 + c4 * 8 + 4] = make_float2(0.0f, 0.0f);
    }
  }
  __syncthreads();

  // ---- Phase C: 16 waves; 0-7 p2-tiles, 8-15 q2-tiles (rows (wv&7)*16) ----
  int wv = t >> 6, lane = t & 63;
  int n16 = lane & 15, quad = lane >> 4;
  int rt = wv & 7;
  bool isQ = wv >= 8;
  f32x4 acc;
#pragma unroll
  for (int r = 0; r < 4; ++r) acc[r] = 0.0f;
  const _Float16* pA = &sH[(rt * 16 + n16) * 68 + quad * 8];
  const _Float16* pB = &sW[((isQ ? 16 : 0) + n16) * 68 + quad * 8];
#pragma unroll
  for (int kc = 0; kc < 2; ++kc) {
    union { f16x8 v; float2 f2[2]; } a, bb;
    a.f2[0] = *(const float2*)(pA + kc * 32);
    a.f2[1] = *(const float2*)(pA + kc * 32 + 4);
    bb.f2[0] = *(const float2*)(pB + kc * 32);
    bb.f2[1] = *(const float2*)(pB + kc * 32 + 4);
    acc = __builtin_amdgcn_mfma_f32_16x16x32_f16(a.v, bb.v, acc, 0, 0, 0);
  }
  if (!isQ) {
#pragma unroll
    for (int r = 0; r < 4; ++r) {
      int row = rt * 16 + quad * 4 + r;
      int n = (b << BSH) + row;
      if (n < N_NODES) p2[(size_t)n * 16 + n16] = __float2half(acc[r]);
    }
  } else {
    float bias = b2[n16];
#pragma unroll
    for (int r = 0; r < 4; ++r) {
      int row = rt * 16 + quad * 4 + r;
      int n = (b << BSH) + row;
      if (n < N_NODES) q2[(size_t)n * 16 + n16] = acc[r] + bias;
    }
  }
}

// ---------------------------------------------------------------------------
// Fuse 2: out[n] = mean_j p2[csr_j] + q2[n].
// float4 gathers, 2 lanes/node, 8-deep unroll.
// ---------------------------------------------------------------------------
__global__ __launch_bounds__(256) void k_fuse2(
    const float4* __restrict__ p2, const float4* __restrict__ q2,
    const int* __restrict__ rowstart, const int* __restrict__ cnt,
    const int* __restrict__ csr, float4* __restrict__ out) {
  int t = threadIdx.x;
  int n = blockIdx.x * 128 + (t >> 1);
  if (n >= N_NODES) return;
  int c8 = t & 1;
  int row = rowstart[n];
  int deg = cnt[n];
  float acc[8];
#pragma unroll
  for (int m = 0; m < 8; ++m) acc[m] = 0.0f;
  int j = 0;
  for (; j + 8 <= deg; j += 8) {
    int idx[8];
#pragma unroll
    for (int u = 0; u < 8; ++u) idx[u] = csr[row + j + u];
    float4 av[8];
#pragma unroll
    for (int u = 0; u < 8; ++u) av[u] = p2[idx[u] * 2 + c8];
#pragma unroll
    for (int u = 0; u < 8; ++u) {
      const __half2* h = (const __half2*)&av[u];
#pragma unroll
      for (int m = 0; m < 4; ++m) {
        float2 f = __half22float2(h[m]);
        acc[2 * m] += f.x;
        acc[2 * m + 1] += f.y;
      }
    }
  }
  for (; j < deg; ++j) {
    float4 a = p2[csr[row + j] * 2 + c8];
    const __half2* h = (const __half2*)&a;
#pragma unroll
    for (int m = 0; m < 4; ++m) {
      float2 f = __half22float2(h[m]);
      acc[2 * m] += f.x;
      acc[2 * m + 1] += f.y;
    }
  }
  float inv = 1.0f / fmaxf((float)deg, 1.0f);
  float4 q0 = q2[n * 4 + c8 * 2];
  float4 q1v = q2[n * 4 + c8 * 2 + 1];
  float4 o0 = {acc[0] * inv + q0.x, acc[1] * inv + q0.y,
               acc[2] * inv + q0.z, acc[3] * inv + q0.w};
  float4 o1 = {acc[4] * inv + q1v.x, acc[5] * inv + q1v.y,
               acc[6] * inv + q1v.z, acc[7] * inv + q1v.w};
  out[n * 4 + c8 * 2] = o0;
  out[n * 4 + c8 * 2 + 1] = o1;
}

extern "C" void kernel_launch(void* const* d_in, const int* in_sizes, int n_in,
                              void* d_out, int out_size, void* d_ws, size_t ws_size,
                              hipStream_t stream) {
  const float* x   = (const float*)d_in[0];
  const int* edge  = (const int*)d_in[1];
  const int* src   = edge;            // edge_index[0]
  const int* dst   = edge + N_EDGES;  // edge_index[1]
  const float* W1l = (const float*)d_in[2];
  const float* b1  = (const float*)d_in[3];
  const float* W1r = (const float*)d_in[4];
  const float* W2l = (const float*)d_in[5];
  const float* b2  = (const float*)d_in[6];
  const float* W2r = (const float*)d_in[7];
  float* out = (float*)d_out;

  // workspace layout (4-byte units; fp16 bases 16B aligned)
  int* gcnt     = (int*)d_ws;          // NBKT (padded to 1024)
  int* rowstart = gcnt + 1024;         // 100000
  int* cnt      = rowstart + N_NODES;  // 100000
  int* binned   = cnt + N_NODES;       // NBKT*CAP = 2001920
  int* csr      = binned + NBKT * CAP; // 2001920
  __half* p1    = (__half*)(csr + NBKT * CAP);  // 6.4M halves (12.8 MB)
  __half* q1    = p1 + (size_t)N_NODES * 64;    // 6.4M halves (12.8 MB)
  __half* p2    = q1 + (size_t)N_NODES * 64;    // 1.6M halves (3.2 MB)
  float* q2     = (float*)(p2 + (size_t)N_NODES * 16);  // 1.6M floats (6.4 MB)

  hipMemsetAsync(gcnt, 0, NBKT * sizeof(int), stream);

  // 1: bin ∪ gemm1 (independent, one dispatch; bin blocks first)
  k_merged1<<<GB + G1B, 256, 0, stream>>>(src, dst, gcnt, binned,
                                          x, W1l, W1r, b1, p1, q1);
  // 2: finalize ∪ fuse1 ∪ gemm2 (128-node bucket per block, 1024 thr)
  k_fuse1c<<<NBKT, 1024, 0, stream>>>((const float4*)p1, gcnt, binned,
                                      W2l, W2r, b2, (const float4*)q1,
                                      csr, rowstart, cnt, p2, q2);
  // 3: fuse2
  k_fuse2<<<(N_NODES + 127) / 128, 256, 0, stream>>>((const float4*)p2,
                                                     (const float4*)q2,
                                                     rowstart, cnt, csr,
                                                     (float4*)out);
}

// Round 15
// 185.207 us; speedup vs baseline: 1.0566x; 1.0566x over previous
//
#include <hip/hip_runtime.h>
#include <hip/hip_fp16.h>

#define N_NODES 100000
#define N_EDGES 1600000
#define IN_C 64
#define HID_C 64
#define OUT_C 16

#define BKT 256        // nodes per dst bucket
#define BSH 8          // dst >> 8 = bucket
#define NBKT 391       // ceil(100000/256)
#define CAP 5120       // slots per bucket (mean 4092, +16 sigma margin)
#define GB 512         // bin sub-blocks in merged pass 1
#define EPB 3125       // edges per bin block (512*3125 = 1.6M exact)
#define NIT 13         // ceil(EPB/256) register-cached edges per thread
#define G1B 1563       // gemm1 sub-blocks = ceil(100000/64)

typedef _Float16 f16x8 __attribute__((ext_vector_type(8)));
typedef float f32x4 __attribute__((ext_vector_type(4)));
typedef float f32x16 __attribute__((ext_vector_type(16)));

// ---------------------------------------------------------------------------
// Merged pass 1: blocks [0,GB) bin edges; blocks [GB, GB+G1B) do GEMM1 (MFMA).
// Bin: dst/src register-cached (one global read pass), LDS bucket histogram ->
// one global atomicAdd per (block,bucket) reserves bucket range -> scatter.
// ---------------------------------------------------------------------------
__global__ __launch_bounds__(256) void k_merged1(
    const int* __restrict__ src, const int* __restrict__ dst,
    int* __restrict__ gcnt, int* __restrict__ binned,
    const float* __restrict__ x, const float* __restrict__ Wl,
    const float* __restrict__ Wr, const float* __restrict__ b,
    __half* __restrict__ p, __half* __restrict__ q) {
  __shared__ _Float16 sA[64 * 68];    // gemm: [row][k]   | bin: h[] alias
  __shared__ _Float16 sW[128 * 68];   // gemm: [col][k]^T | bin: cur[] alias
  int t = threadIdx.x;

  if (blockIdx.x < GB) {
    int* h   = (int*)sA;              // NBKT ints
    int* cur = (int*)sW;              // NBKT ints
    for (int i = t; i < NBKT; i += 256) h[i] = 0;
    __syncthreads();
    int base = blockIdx.x * EPB;
    int end = base + EPB;
    int dv[NIT], sv[NIT];
#pragma unroll
    for (int it = 0; it < NIT; ++it) {
      int e = base + t + it * 256;
      bool ok = (e < end);
      dv[it] = ok ? dst[e] : -1;
      sv[it] = ok ? src[e] : 0;
    }
#pragma unroll
    for (int it = 0; it < NIT; ++it)
      if (dv[it] >= 0) atomicAdd(&h[dv[it] >> BSH], 1);
    __syncthreads();
    for (int i = t; i < NBKT; i += 256) {
      int c = h[i];
      int b0 = (c > 0) ? atomicAdd(&gcnt[i], c) : 0;  // reserve range
      cur[i] = i * CAP + b0;
    }
    __syncthreads();
#pragma unroll
    for (int it = 0; it < NIT; ++it) {
      if (dv[it] >= 0) {
        int d = dv[it];
        int pos = atomicAdd(&cur[d >> BSH], 1);
        binned[pos] = (sv[it] << BSH) | (d & (BKT - 1));
      }
    }
    return;
  }

  // ---------------- gemm1 body ----------------
  int n0 = (blockIdx.x - GB) * 64;

  for (int f = t; f < 1024; f += 256) {
    int r = f >> 4, c4 = f & 15;
    int n = n0 + r;
    float4 v = {0.0f, 0.0f, 0.0f, 0.0f};
    if (n < N_NODES) v = *(const float4*)&x[(size_t)n * 64 + c4 * 4];
    union { _Float16 h[4]; float2 f2; } u;
    u.h[0] = (_Float16)v.x; u.h[1] = (_Float16)v.y;
    u.h[2] = (_Float16)v.z; u.h[3] = (_Float16)v.w;
    *(float2*)&sA[r * 68 + c4 * 4] = u.f2;
  }
  for (int f = t; f < 2048; f += 256) {
    int k = f >> 5, c4 = f & 31;
    float4 w = (c4 < 16) ? *(const float4*)&Wl[k * 64 + c4 * 4]
                         : *(const float4*)&Wr[k * 64 + (c4 - 16) * 4];
    int c = c4 * 4;
    sW[(c + 0) * 68 + k] = (_Float16)w.x;
    sW[(c + 1) * 68 + k] = (_Float16)w.y;
    sW[(c + 2) * 68 + k] = (_Float16)w.z;
    sW[(c + 3) * 68 + k] = (_Float16)w.w;
  }
  __syncthreads();

  int w = t >> 6, lane = t & 63;
  int m = lane & 31, half = lane >> 5;
  int rt = w & 1, cg = w >> 1;

  f32x16 acc[2];
#pragma unroll
  for (int r = 0; r < 16; ++r) { acc[0][r] = 0.0f; acc[1][r] = 0.0f; }

  const _Float16* pA = &sA[(rt * 32 + m) * 68 + half * 8];
  const _Float16* pB0 = &sW[(cg * 64 + m) * 68 + half * 8];
  const _Float16* pB1 = &sW[(cg * 64 + 32 + m) * 68 + half * 8];
#pragma unroll
  for (int kc = 0; kc < 4; ++kc) {
    union { f16x8 v; float2 f2[2]; } a, b0, b1;
    a.f2[0] = *(const float2*)(pA + kc * 16);
    a.f2[1] = *(const float2*)(pA + kc * 16 + 4);
    b0.f2[0] = *(const float2*)(pB0 + kc * 16);
    b0.f2[1] = *(const float2*)(pB0 + kc * 16 + 4);
    b1.f2[0] = *(const float2*)(pB1 + kc * 16);
    b1.f2[1] = *(const float2*)(pB1 + kc * 16 + 4);
    acc[0] = __builtin_amdgcn_mfma_f32_32x32x16_f16(a.v, b0.v, acc[0], 0, 0, 0);
    acc[1] = __builtin_amdgcn_mfma_f32_32x32x16_f16(a.v, b1.v, acc[1], 0, 0, 0);
  }

  if (cg == 0) {
#pragma unroll
    for (int tt = 0; tt < 2; ++tt) {
      int col = tt * 32 + m;
#pragma unroll
      for (int r = 0; r < 16; ++r) {
        int row = (r & 3) + 4 * half + 8 * (r >> 2);
        int n = n0 + rt * 32 + row;
        if (n < N_NODES) p[(size_t)n * 64 + col] = __float2half(acc[tt][r]);
      }
    }
  } else {
    float bias[2] = {b[m], b[32 + m]};
#pragma unroll
    for (int tt = 0; tt < 2; ++tt) {
      int col = tt * 32 + m;
#pragma unroll
      for (int r = 0; r < 16; ++r) {
        int row = (r & 3) + 4 * half + 8 * (r >> 2);
        int n = n0 + rt * 32 + row;
        if (n < N_NODES)
          q[(size_t)n * 64 + col] = __float2half(acc[tt][r] + bias[tt]);
      }
    }
  }
}

// ---------------------------------------------------------------------------
// Fuse1c (finalize ∪ fuse1 ∪ gemm2): one block per 256-node bucket, 1024 thr.
// Phase A: node histogram -> LDS scan -> scatter src into LDS lcsr;
//          export csr/rowstart/cnt for fuse2.
// Phase B: h = relu(mean_j p1[lcsr_j] + q1) -> fp16 LDS sH (128 groups x
//          2 nodes, 8 lanes x float4); zero-pad tail rows.
// Phase C: MFMA 256x32 K=64: 16 waves x one 16-row tile,
//          mfma_f32_16x16x32_f16; cols 0-15 -> p2, 16-31 -> q2+bias.
// ---------------------------------------------------------------------------
__global__ __launch_bounds__(1024) void k_fuse1c(
    const float4* __restrict__ p1, const int* __restrict__ gcnt,
    const int* __restrict__ binned, const float* __restrict__ W2l,
    const float* __restrict__ W2r, const float* __restrict__ b2,
    const float4* __restrict__ q1, int* __restrict__ csr,
    int* __restrict__ rowstart, int* __restrict__ cnt,
    __half* __restrict__ p2, float* __restrict__ q2) {
  __shared__ int hcnt[BKT];
  __shared__ int hscan[BKT];
  __shared__ int cur[BKT];
  __shared__ int lcsr[CAP];          // 20 KB
  __shared__ _Float16 sH[256 * 68];  // 34.8 KB
  __shared__ _Float16 sW[32 * 68];   // 4.4 KB [col][k]^T: 0-15 W2l, 16-31 W2r
  int b = blockIdx.x;
  int t = threadIdx.x;

  if (t < 512) {  // stage W2^T (512 half4 chunks)
    int k = t >> 3, c4v = t & 7;
    float4 w = (c4v < 4) ? *(const float4*)&W2l[k * 16 + c4v * 4]
                         : *(const float4*)&W2r[k * 16 + (c4v - 4) * 4];
    int c = c4v * 4;
    sW[(c + 0) * 68 + k] = (_Float16)w.x;
    sW[(c + 1) * 68 + k] = (_Float16)w.y;
    sW[(c + 2) * 68 + k] = (_Float16)w.z;
    sW[(c + 3) * 68 + k] = (_Float16)w.w;
  }
  if (t < BKT) hcnt[t] = 0;
  __syncthreads();

  // ---- Phase A ----
  int start = b * CAP;
  int total = gcnt[b];
  for (int i = t; i < total; i += 1024)
    atomicAdd(&hcnt[binned[start + i] & (BKT - 1)], 1);
  __syncthreads();
  int v = 0;
  if (t < BKT) {
    v = hcnt[t];
    hscan[t] = v;
  }
  __syncthreads();
  for (int st = 1; st < BKT; st <<= 1) {
    int a = 0;
    if (t < BKT && t >= st) a = hscan[t - st];
    __syncthreads();
    if (t < BKT) hscan[t] += a;
    __syncthreads();
  }
  if (t < BKT) {
    cur[t] = hscan[t] - v;          // local exclusive start
    int n = (b << BSH) + t;
    if (n < N_NODES) {
      rowstart[n] = start + hscan[t] - v;
      cnt[n] = v;
    }
  }
  __syncthreads();
  for (int i = t; i < total; i += 1024) {
    int vv = binned[start + i];
    int pos = atomicAdd(&cur[vv & (BKT - 1)], 1);
    lcsr[pos] = vv >> BSH;
  }
  __syncthreads();
  for (int i = t; i < total; i += 1024) csr[start + i] = lcsr[i];  // for fuse2

  // ---- Phase B: aggregate + relu -> sH (fp16); 128 groups x 2 nodes ----
  int g = t >> 3, c4 = t & 7;
  for (int r = g; r < BKT; r += 128) {
    int n = (b << BSH) + r;
    if (n < N_NODES) {
      int deg = hcnt[r];
      int row = hscan[r] - deg;  // local start in lcsr
      float acc[8];
#pragma unroll
      for (int m = 0; m < 8; ++m) acc[m] = 0.0f;
      int j = 0;
      for (; j + 8 <= deg; j += 8) {
        int idx[8];
#pragma unroll
        for (int u = 0; u < 8; ++u) idx[u] = lcsr[row + j + u];
        float4 av[8];
#pragma unroll
        for (int u = 0; u < 8; ++u) av[u] = p1[idx[u] * 8 + c4];
#pragma unroll
        for (int u = 0; u < 8; ++u) {
          const __half2* h = (const __half2*)&av[u];
#pragma unroll
          for (int m = 0; m < 4; ++m) {
            float2 f = __half22float2(h[m]);
            acc[2 * m] += f.x;
            acc[2 * m + 1] += f.y;
          }
        }
      }
      for (; j < deg; ++j) {
        float4 a = p1[lcsr[row + j] * 8 + c4];
        const __half2* h = (const __half2*)&a;
#pragma unroll
        for (int m = 0; m < 4; ++m) {
          float2 f = __half22float2(h[m]);
          acc[2 * m] += f.x;
          acc[2 * m + 1] += f.y;
        }
      }
      float inv = 1.0f / fmaxf((float)deg, 1.0f);
      float4 qv = q1[n * 8 + c4];
      __half2* qh = (__half2*)&qv;
      union { __half2 h2[2]; float2 f2; } u01, u23;
#pragma unroll
      for (int m = 0; m < 2; ++m) {
        float2 f = __half22float2(qh[m]);
        float2 s;
        s.x = fmaxf(acc[2 * m] * inv + f.x, 0.0f);
        s.y = fmaxf(acc[2 * m + 1] * inv + f.y, 0.0f);
        u01.h2[m] = __float22half2_rn(s);
      }
#pragma unroll
      for (int m = 2; m < 4; ++m) {
        float2 f = __half22float2(qh[m]);
        float2 s;
        s.x = fmaxf(acc[2 * m] * inv + f.x, 0.0f);
        s.y = fmaxf(acc[2 * m + 1] * inv + f.y, 0.0f);
        u23.h2[m - 2] = __float22half2_rn(s);
      }
      *(float2*)&sH[r * 68 + c4 * 8] = u01.f2;
      *(float2*)&sH[r * 68 + c4 * 8 + 4] = u23.f2;
    } else {
      // zero pad rows beyond N_NODES so phase C MFMA reads defined data
      *(float2*)&sH[r * 68 + c4 * 8] = make_float2(0.0f, 0.0f);
      *(float2*)&sH[r * 68 + c4 * 8 + 4] = make_float2(0.0f, 0.0f);
    }
  }
  __syncthreads();

  // ---- Phase C: 16 waves, one 16-row tile each; p2 and q2 per wave ----
  int wv = t >> 6, lane = t & 63;
  int n16 = lane & 15, quad = lane >> 4;
  f32x4 aP, aQ;
#pragma unroll
  for (int r = 0; r < 4; ++r) { aP[r] = 0.0f; aQ[r] = 0.0f; }
  const _Float16* pA = &sH[(wv * 16 + n16) * 68 + quad * 8];
  const _Float16* pBP = &sW[n16 * 68 + quad * 8];
  const _Float16* pBQ = &sW[(16 + n16) * 68 + quad * 8];
#pragma unroll
  for (int kc = 0; kc < 2; ++kc) {
    union { f16x8 v; float2 f2[2]; } a, bp, bq;
    a.f2[0] = *(const float2*)(pA + kc * 32);
    a.f2[1] = *(const float2*)(pA + kc * 32 + 4);
    bp.f2[0] = *(const float2*)(pBP + kc * 32);
    bp.f2[1] = *(const float2*)(pBP + kc * 32 + 4);
    bq.f2[0] = *(const float2*)(pBQ + kc * 32);
    bq.f2[1] = *(const float2*)(pBQ + kc * 32 + 4);
    aP = __builtin_amdgcn_mfma_f32_16x16x32_f16(a.v, bp.v, aP, 0, 0, 0);
    aQ = __builtin_amdgcn_mfma_f32_16x16x32_f16(a.v, bq.v, aQ, 0, 0, 0);
  }
  float bias = b2[n16];
#pragma unroll
  for (int r = 0; r < 4; ++r) {
    int row = wv * 16 + quad * 4 + r;
    int n = (b << BSH) + row;
    if (n < N_NODES) {
      p2[(size_t)n * 16 + n16] = __float2half(aP[r]);
      q2[(size_t)n * 16 + n16] = aQ[r] + bias;
    }
  }
}

// ---------------------------------------------------------------------------
// Fuse 2: out[n] = mean_j p2[csr_j] + q2[n].
// float4 gathers, 2 lanes/node, 8-deep unroll.
// ---------------------------------------------------------------------------
__global__ __launch_bounds__(256) void k_fuse2(
    const float4* __restrict__ p2, const float4* __restrict__ q2,
    const int* __restrict__ rowstart, const int* __restrict__ cnt,
    const int* __restrict__ csr, float4* __restrict__ out) {
  int t = threadIdx.x;
  int n = blockIdx.x * 128 + (t >> 1);
  if (n >= N_NODES) return;
  int c8 = t & 1;
  int row = rowstart[n];
  int deg = cnt[n];
  float acc[8];
#pragma unroll
  for (int m = 0; m < 8; ++m) acc[m] = 0.0f;
  int j = 0;
  for (; j + 8 <= deg; j += 8) {
    int idx[8];
#pragma unroll
    for (int u = 0; u < 8; ++u) idx[u] = csr[row + j + u];
    float4 av[8];
#pragma unroll
    for (int u = 0; u < 8; ++u) av[u] = p2[idx[u] * 2 + c8];
#pragma unroll
    for (int u = 0; u < 8; ++u) {
      const __half2* h = (const __half2*)&av[u];
#pragma unroll
      for (int m = 0; m < 4; ++m) {
        float2 f = __half22float2(h[m]);
        acc[2 * m] += f.x;
        acc[2 * m + 1] += f.y;
      }
    }
  }
  for (; j < deg; ++j) {
    float4 a = p2[csr[row + j] * 2 + c8];
    const __half2* h = (const __half2*)&a;
#pragma unroll
    for (int m = 0; m < 4; ++m) {
      float2 f = __half22float2(h[m]);
      acc[2 * m] += f.x;
      acc[2 * m + 1] += f.y;
    }
  }
  float inv = 1.0f / fmaxf((float)deg, 1.0f);
  float4 q0 = q2[n * 4 + c8 * 2];
  float4 q1v = q2[n * 4 + c8 * 2 + 1];
  float4 o0 = {acc[0] * inv + q0.x, acc[1] * inv + q0.y,
               acc[2] * inv + q0.z, acc[3] * inv + q0.w};
  float4 o1 = {acc[4] * inv + q1v.x, acc[5] * inv + q1v.y,
               acc[6] * inv + q1v.z, acc[7] * inv + q1v.w};
  out[n * 4 + c8 * 2] = o0;
  out[n * 4 + c8 * 2 + 1] = o1;
}

extern "C" void kernel_launch(void* const* d_in, const int* in_sizes, int n_in,
                              void* d_out, int out_size, void* d_ws, size_t ws_size,
                              hipStream_t stream) {
  const float* x   = (const float*)d_in[0];
  const int* edge  = (const int*)d_in[1];
  const int* src   = edge;            // edge_index[0]
  const int* dst   = edge + N_EDGES;  // edge_index[1]
  const float* W1l = (const float*)d_in[2];
  const float* b1  = (const float*)d_in[3];
  const float* W1r = (const float*)d_in[4];
  const float* W2l = (const float*)d_in[5];
  const float* b2  = (const float*)d_in[6];
  const float* W2r = (const float*)d_in[7];
  float* out = (float*)d_out;

  // workspace layout (4-byte units; fp16 bases 16B aligned)
  int* gcnt     = (int*)d_ws;          // NBKT (padded to 512)
  int* rowstart = gcnt + 512;          // 100000
  int* cnt      = rowstart + N_NODES;  // 100000
  int* binned   = cnt + N_NODES;       // NBKT*CAP = 2001920
  int* csr      = binned + NBKT * CAP; // 2001920
  __half* p1    = (__half*)(csr + NBKT * CAP);  // 6.4M halves (12.8 MB)
  __half* q1    = p1 + (size_t)N_NODES * 64;    // 6.4M halves (12.8 MB)
  __half* p2    = q1 + (size_t)N_NODES * 64;    // 1.6M halves (3.2 MB)
  float* q2     = (float*)(p2 + (size_t)N_NODES * 16);  // 1.6M floats (6.4 MB)

  hipMemsetAsync(gcnt, 0, NBKT * sizeof(int), stream);

  // 1: bin ∪ gemm1 (independent, one dispatch; bin blocks first)
  k_merged1<<<GB + G1B, 256, 0, stream>>>(src, dst, gcnt, binned,
                                          x, W1l, W1r, b1, p1, q1);
  // 2: finalize ∪ fuse1 ∪ gemm2 (256-node bucket per block, 1024 thr)
  k_fuse1c<<<NBKT, 1024, 0, stream>>>((const float4*)p1, gcnt, binned,
                                      W2l, W2r, b2, (const float4*)q1,
                                      csr, rowstart, cnt, p2, q2);
  // 3: fuse2
  k_fuse2<<<(N_NODES + 127) / 128, 256, 0, stream>>>((const float4*)p2,
                                                     (const float4*)q2,
                                                     rowstart, cnt, csr,
                                                     (float4*)out);
}